// Round 1
// baseline (10617.123 us; speedup 1.0000x reference)
//
#include <hip/hip_runtime.h>
#include <math.h>

#define EMB   1024
#define HEADS 16
#define HD    64
#define SEQ   2048
#define BATCH 4
#define MTOT  (BATCH * SEQ)   // 8192 rows

// ---------------------------------------------------------------------------
// GEMM: Y[m,n] = sum_k X[m,k] * W[n,k]  (+ bias[n])   i.e. Y = X @ W^T
// Both X and W are k-contiguous -> fully coalesced float4 loads.
// 64x64 block tile, K-tile 16, 256 threads, 4x4 accumulators per thread.
// LDS padded to 17 floats/row: inner-loop reads are 2-way bank aliased (free).
// ---------------------------------------------------------------------------
__global__ __launch_bounds__(256)
void gemm_xwt(const float* __restrict__ X, const float* __restrict__ W,
              float* __restrict__ Y, const float* __restrict__ bias,
              int M, int N, int Kd)
{
    __shared__ float As[64][17];
    __shared__ float Bs[64][17];

    const int tid = threadIdx.x;
    const int tx  = tid & 15;        // 0..15 -> output col group
    const int ty  = tid >> 4;        // 0..15 -> output row group
    const int rowBase = blockIdx.y * 64;
    const int colBase = blockIdx.x * 64;

    // staging: each thread loads one float4 of X and one of W per K-tile
    const int lr = tid >> 2;         // 0..63 tile row
    const int lc = (tid & 3) * 4;    // 0,4,8,12 k offset

    float acc[4][4] = {{0.f}};

    for (int k0 = 0; k0 < Kd; k0 += 16) {
        const float4 xv = *(const float4*)&X[(size_t)(rowBase + lr) * Kd + k0 + lc];
        const float4 wv = *(const float4*)&W[(size_t)(colBase + lr) * Kd + k0 + lc];
        As[lr][lc + 0] = xv.x; As[lr][lc + 1] = xv.y;
        As[lr][lc + 2] = xv.z; As[lr][lc + 3] = xv.w;
        Bs[lr][lc + 0] = wv.x; Bs[lr][lc + 1] = wv.y;
        Bs[lr][lc + 2] = wv.z; Bs[lr][lc + 3] = wv.w;
        __syncthreads();

#pragma unroll
        for (int kk = 0; kk < 16; ++kk) {
            float a[4], b[4];
#pragma unroll
            for (int ii = 0; ii < 4; ++ii) a[ii] = As[ty * 4 + ii][kk];
#pragma unroll
            for (int jj = 0; jj < 4; ++jj) b[jj] = Bs[tx * 4 + jj][kk];
#pragma unroll
            for (int ii = 0; ii < 4; ++ii)
#pragma unroll
                for (int jj = 0; jj < 4; ++jj)
                    acc[ii][jj] += a[ii] * b[jj];
        }
        __syncthreads();
    }

#pragma unroll
    for (int ii = 0; ii < 4; ++ii) {
        const int r = rowBase + ty * 4 + ii;
#pragma unroll
        for (int jj = 0; jj < 4; ++jj) {
            const int c = colBase + tx * 4 + jj;
            float v = acc[ii][jj];
            if (bias) v += bias[c];
            Y[(size_t)r * N + c] = v;
        }
    }
}

// ---------------------------------------------------------------------------
// Causal attention, one wave per (b, h, query-row i). lane = head dim d.
// Online softmax; the softmax branch is wave-uniform (score is reduced to all
// lanes), so no divergence. K/V row loads are 256B coalesced.
// O aliases Q: each wave reads only its own Q row (before its own write), and
// writes only its own O row -> no cross-wave hazard.
// ---------------------------------------------------------------------------
__global__ __launch_bounds__(256)
void attn_causal(const float* __restrict__ Q, const float* __restrict__ K,
                 const float* __restrict__ V, float* __restrict__ O)
{
    const int wave = (int)((blockIdx.x * blockDim.x + threadIdx.x) >> 6);
    const int lane = threadIdx.x & 63;
    const int bh   = wave >> 11;        // / SEQ
    const int i    = wave & (SEQ - 1);
    const int b    = bh >> 4;           // / HEADS
    const int h    = bh & (HEADS - 1);

    const size_t rowQ = ((size_t)(b * SEQ + i)) * EMB + h * HD;
    const float q = Q[rowQ + lane] * 0.125f;   // 1/sqrt(64)

    const size_t base = ((size_t)b * SEQ) * EMB + h * HD + lane;

    float m = -3.0e38f, l = 0.f, acc = 0.f;

    for (int j = 0; j <= i; ++j) {
        float p = q * K[base + (size_t)j * EMB];
#pragma unroll
        for (int off = 32; off; off >>= 1) p += __shfl_xor(p, off, 64);
        const float vv = V[base + (size_t)j * EMB];
        if (p <= m) {                      // wave-uniform branch
            const float e = __expf(p - m);
            l   += e;
            acc += e * vv;
        } else {
            const float c = __expf(m - p); // first iter: underflows to 0
            l   = l * c + 1.f;
            acc = acc * c + vv;
            m   = p;
        }
    }

    O[rowQ + lane] = acc / l;
}

// ---------------------------------------------------------------------------
extern "C" void kernel_launch(void* const* d_in, const int* in_sizes, int n_in,
                              void* d_out, int out_size, void* d_ws, size_t ws_size,
                              hipStream_t stream)
{
    const float* x  = (const float*)d_in[0];
    const float* Wq = (const float*)d_in[1];
    const float* Wk = (const float*)d_in[2];
    const float* Wv = (const float*)d_in[3];
    const float* Wo = (const float*)d_in[4];
    const float* bo = (const float*)d_in[5];
    float* out = (float*)d_out;

    const size_t mat = (size_t)MTOT * EMB;     // 8.4M floats = 32 MiB
    float* Qb = (float*)d_ws;
    float* Kb = Qb + mat;
    float* Vb = Kb + mat;                      // total 96 MiB of d_ws

    const dim3 gemm_grid(EMB / 64, MTOT / 64); // (16, 128)
    const dim3 gemm_blk(256);

    gemm_xwt<<<gemm_grid, gemm_blk, 0, stream>>>(x, Wq, Qb, nullptr, MTOT, EMB, EMB);
    gemm_xwt<<<gemm_grid, gemm_blk, 0, stream>>>(x, Wk, Kb, nullptr, MTOT, EMB, EMB);
    gemm_xwt<<<gemm_grid, gemm_blk, 0, stream>>>(x, Wv, Vb, nullptr, MTOT, EMB, EMB);

    // one wave per (b,h,i): 4*16*2048 = 131072 waves, 4 waves/block
    attn_causal<<<(MTOT * HEADS) / 4, 256, 0, stream>>>(Qb, Kb, Vb, Qb);

    gemm_xwt<<<gemm_grid, gemm_blk, 0, stream>>>(Qb, Wo, out, bo, MTOT, EMB, EMB);
}

// Round 2
// 1672.416 us; speedup vs baseline: 6.3484x; 6.3484x over previous
//
#include <hip/hip_runtime.h>
#include <math.h>

#define EMB   1024
#define HEADS 16
#define HD    64
#define SEQ   2048
#define BATCH 4
#define MTOT  (BATCH * SEQ)   // 8192 rows

typedef __attribute__((ext_vector_type(8))) short s16x8;
typedef __attribute__((ext_vector_type(4))) short s16x4;
typedef __attribute__((ext_vector_type(4))) float f32x4;

// LDS row strides (bf16 elements). 72*2=144B: 16B-aligned for ds_read_b128,
// and per-instruction bank load is exactly even (1024B/32banks = floor).
#define LK_S 72
#define LV_S 72
#define LP_S 72

__device__ __forceinline__ short f2bf(float f) {
    unsigned u = __builtin_bit_cast(unsigned, f);
    u += 0x7fffu + ((u >> 16) & 1u);     // RNE
    return (short)(u >> 16);
}

// ---------------------------------------------------------------------------
// fp32 tiled GEMM: Y = X @ W^T (+bias). Unchanged from round 0.
// ---------------------------------------------------------------------------
__global__ __launch_bounds__(256)
void gemm_xwt(const float* __restrict__ X, const float* __restrict__ W,
              float* __restrict__ Y, const float* __restrict__ bias,
              int M, int N, int Kd)
{
    __shared__ float As[64][17];
    __shared__ float Bs[64][17];

    const int tid = threadIdx.x;
    const int tx  = tid & 15;
    const int ty  = tid >> 4;
    const int rowBase = blockIdx.y * 64;
    const int colBase = blockIdx.x * 64;
    const int lr = tid >> 2;
    const int lc = (tid & 3) * 4;

    float acc[4][4] = {{0.f}};

    for (int k0 = 0; k0 < Kd; k0 += 16) {
        const float4 xv = *(const float4*)&X[(size_t)(rowBase + lr) * Kd + k0 + lc];
        const float4 wv = *(const float4*)&W[(size_t)(colBase + lr) * Kd + k0 + lc];
        As[lr][lc + 0] = xv.x; As[lr][lc + 1] = xv.y;
        As[lr][lc + 2] = xv.z; As[lr][lc + 3] = xv.w;
        Bs[lr][lc + 0] = wv.x; Bs[lr][lc + 1] = wv.y;
        Bs[lr][lc + 2] = wv.z; Bs[lr][lc + 3] = wv.w;
        __syncthreads();

#pragma unroll
        for (int kk = 0; kk < 16; ++kk) {
            float a[4], b[4];
#pragma unroll
            for (int ii = 0; ii < 4; ++ii) a[ii] = As[ty * 4 + ii][kk];
#pragma unroll
            for (int jj = 0; jj < 4; ++jj) b[jj] = Bs[tx * 4 + jj][kk];
#pragma unroll
            for (int ii = 0; ii < 4; ++ii)
#pragma unroll
                for (int jj = 0; jj < 4; ++jj)
                    acc[ii][jj] += a[ii] * b[jj];
        }
        __syncthreads();
    }

#pragma unroll
    for (int ii = 0; ii < 4; ++ii) {
        const int r = rowBase + ty * 4 + ii;
#pragma unroll
        for (int jj = 0; jj < 4; ++jj) {
            const int c = colBase + tx * 4 + jj;
            float v = acc[ii][jj];
            if (bias) v += bias[c];
            Y[(size_t)r * N + c] = v;
        }
    }
}

// ---------------------------------------------------------------------------
// Flash-style causal attention with bf16 MFMA (16x16x32).
// Block: 128 queries of one (b,h); 4 waves x 32 queries (2 row-blocks of 16).
// S^T = K·Q^T so that softmax state lives at query=lane&15 and P packs to
// A-operand layout with one ds_write_b64 per key-subtile.
// O aliases Q (wave reads its own Q rows first; disjoint otherwise).
// ---------------------------------------------------------------------------
__global__ __launch_bounds__(256)
void attn_mfma(const float* __restrict__ Q, const float* __restrict__ K,
               const float* __restrict__ V, float* __restrict__ O)
{
    __shared__ short lK[64 * LK_S];       // lK[key][hd]
    __shared__ short lV[64 * LV_S];       // lV[hd][key]  (transposed)
    __shared__ short lP[8 * 16 * LP_S];   // per (wave,rb): lP[q][key]

    const int tid  = threadIdx.x;
    const int wv   = tid >> 6;
    const int lane = tid & 63;
    const int col  = lane & 15;
    const int quad = lane >> 4;

    const int qb = blockIdx.x * 128;
    const int bh = blockIdx.y;
    const size_t base = (size_t)(bh >> 4) * SEQ * EMB + (size_t)(bh & 15) * HD;

    // Q fragments (B-operand: n=col -> query, k=quad*8+j), scaled by 1/sqrt(64)
    s16x8 qf[2][2];
#pragma unroll
    for (int rb = 0; rb < 2; ++rb) {
        const float* qr = Q + base + (size_t)(qb + wv * 32 + rb * 16 + col) * EMB;
#pragma unroll
        for (int c = 0; c < 2; ++c) {
            const float4 a = *(const float4*)(qr + c * 32 + quad * 8);
            const float4 b = *(const float4*)(qr + c * 32 + quad * 8 + 4);
            s16x8 v;
            v[0] = f2bf(a.x * 0.125f); v[1] = f2bf(a.y * 0.125f);
            v[2] = f2bf(a.z * 0.125f); v[3] = f2bf(a.w * 0.125f);
            v[4] = f2bf(b.x * 0.125f); v[5] = f2bf(b.y * 0.125f);
            v[6] = f2bf(b.z * 0.125f); v[7] = f2bf(b.w * 0.125f);
            qf[rb][c] = v;
        }
    }

    float mrow[2] = {-3.0e38f, -3.0e38f};
    float lrow[2] = {0.f, 0.f};
    f32x4 of[2][4];
#pragma unroll
    for (int rb = 0; rb < 2; ++rb)
#pragma unroll
        for (int u = 0; u < 4; ++u) of[rb][u] = (f32x4){0.f, 0.f, 0.f, 0.f};

    const int nt = qb / 64 + 2;

    for (int kt = 0; kt < nt; ++kt) {
        const int kb = kt * 64;
        __syncthreads();
        // ---- stage K (row-major) and V (transposed) as bf16 ----
        {
            const int r  = tid >> 2;
            const int c0 = (tid & 3) * 16;
            const float* kr = K + base + (size_t)(kb + r) * EMB + c0;
            const float* vr = V + base + (size_t)(kb + r) * EMB + c0;
#pragma unroll
            for (int half = 0; half < 2; ++half) {
                const float4 x0 = *(const float4*)(kr + half * 8);
                const float4 x1 = *(const float4*)(kr + half * 8 + 4);
                s16x8 w;
                w[0] = f2bf(x0.x); w[1] = f2bf(x0.y); w[2] = f2bf(x0.z); w[3] = f2bf(x0.w);
                w[4] = f2bf(x1.x); w[5] = f2bf(x1.y); w[6] = f2bf(x1.z); w[7] = f2bf(x1.w);
                *(s16x8*)&lK[r * LK_S + c0 + half * 8] = w;
            }
#pragma unroll
            for (int u = 0; u < 4; ++u) {
                const float4 x = *(const float4*)(vr + u * 4);
                lV[(c0 + u * 4 + 0) * LV_S + r] = f2bf(x.x);
                lV[(c0 + u * 4 + 1) * LV_S + r] = f2bf(x.y);
                lV[(c0 + u * 4 + 2) * LV_S + r] = f2bf(x.z);
                lV[(c0 + u * 4 + 3) * LV_S + r] = f2bf(x.w);
            }
        }
        __syncthreads();

        // ---- S^T = K·Q^T : C/D row = key(quad*4+reg), col = query ----
        f32x4 s[2][4];
#pragma unroll
        for (int t = 0; t < 4; ++t) {
            const s16x8 kf0 = *(const s16x8*)&lK[(t * 16 + col) * LK_S + quad * 8];
            const s16x8 kf1 = *(const s16x8*)&lK[(t * 16 + col) * LK_S + 32 + quad * 8];
#pragma unroll
            for (int rb = 0; rb < 2; ++rb) {
                f32x4 acc = (f32x4){0.f, 0.f, 0.f, 0.f};
                acc = __builtin_amdgcn_mfma_f32_16x16x32_bf16(kf0, qf[rb][0], acc, 0, 0, 0);
                acc = __builtin_amdgcn_mfma_f32_16x16x32_bf16(kf1, qf[rb][1], acc, 0, 0, 0);
                s[rb][t] = acc;
            }
        }

#pragma unroll
        for (int rb = 0; rb < 2; ++rb) {
            const int qlo = qb + wv * 32 + rb * 16;
            if (kb > qlo + 15) continue;          // tile fully masked for this rb
            const int qg = qlo + col;

            if (kb + 63 > qlo) {                  // diagonal tile: causal mask
#pragma unroll
                for (int t = 0; t < 4; ++t)
#pragma unroll
                    for (int r = 0; r < 4; ++r) {
                        const int kg = kb + t * 16 + quad * 4 + r;
                        if (kg > qg) s[rb][t][r] = -3.0e38f;
                    }
            }

            // row max over 64 keys (16 local + cross-quad shuffles)
            float mx = s[rb][0][0];
#pragma unroll
            for (int t = 0; t < 4; ++t)
#pragma unroll
                for (int r = 0; r < 4; ++r) mx = fmaxf(mx, s[rb][t][r]);
            mx = fmaxf(mx, __shfl_xor(mx, 16, 64));
            mx = fmaxf(mx, __shfl_xor(mx, 32, 64));
            const float mnew = fmaxf(mrow[rb], mx);

            float sum = 0.f;
#pragma unroll
            for (int t = 0; t < 4; ++t)
#pragma unroll
                for (int r = 0; r < 4; ++r) {
                    const float p = __expf(s[rb][t][r] - mnew);
                    s[rb][t][r] = p;
                    sum += p;
                }
            sum += __shfl_xor(sum, 16, 64);
            sum += __shfl_xor(sum, 32, 64);

            const float alpha = __expf(mrow[rb] - mnew);
            lrow[rb] = lrow[rb] * alpha + sum;
            mrow[rb] = mnew;

            // pack P (bf16) into A-operand staging: lP[q][key]
            short* pbase = &lP[((wv * 2 + rb) * 16) * LP_S];
#pragma unroll
            for (int t = 0; t < 4; ++t) {
                s16x4 pk;
                pk[0] = f2bf(s[rb][t][0]); pk[1] = f2bf(s[rb][t][1]);
                pk[2] = f2bf(s[rb][t][2]); pk[3] = f2bf(s[rb][t][3]);
                *(s16x4*)&pbase[col * LP_S + t * 16 + quad * 4] = pk;
            }

            // rescale O accumulator (alpha per C/D row = query quad*4+reg)
            const float a0 = __shfl(alpha, quad * 4 + 0, 64);
            const float a1 = __shfl(alpha, quad * 4 + 1, 64);
            const float a2 = __shfl(alpha, quad * 4 + 2, 64);
            const float a3 = __shfl(alpha, quad * 4 + 3, 64);
#pragma unroll
            for (int u = 0; u < 4; ++u) {
                of[rb][u][0] *= a0; of[rb][u][1] *= a1;
                of[rb][u][2] *= a2; of[rb][u][3] *= a3;
            }

            // PV: A = P[q][key], B = V[key][d] (from lV[d][key])
#pragma unroll
            for (int c = 0; c < 2; ++c) {
                const s16x8 pa = *(const s16x8*)&pbase[col * LP_S + c * 32 + quad * 8];
#pragma unroll
                for (int u = 0; u < 4; ++u) {
                    const s16x8 vf = *(const s16x8*)&lV[(u * 16 + col) * LV_S + c * 32 + quad * 8];
                    of[rb][u] = __builtin_amdgcn_mfma_f32_16x16x32_bf16(pa, vf, of[rb][u], 0, 0, 0);
                }
            }
        }
    }

    // ---- epilogue: normalize and store ----
#pragma unroll
    for (int rb = 0; rb < 2; ++rb) {
        const float rl = 1.f / lrow[rb];
        const float r0 = __shfl(rl, quad * 4 + 0, 64);
        const float r1 = __shfl(rl, quad * 4 + 1, 64);
        const float r2 = __shfl(rl, quad * 4 + 2, 64);
        const float r3 = __shfl(rl, quad * 4 + 3, 64);
        const int q0 = qb + wv * 32 + rb * 16 + quad * 4;
        float* o0 = O + base + (size_t)(q0 + 0) * EMB;
        float* o1 = O + base + (size_t)(q0 + 1) * EMB;
        float* o2 = O + base + (size_t)(q0 + 2) * EMB;
        float* o3 = O + base + (size_t)(q0 + 3) * EMB;
#pragma unroll
        for (int u = 0; u < 4; ++u) {
            o0[u * 16 + col] = of[rb][u][0] * r0;
            o1[u * 16 + col] = of[rb][u][1] * r1;
            o2[u * 16 + col] = of[rb][u][2] * r2;
            o3[u * 16 + col] = of[rb][u][3] * r3;
        }
    }
}

// ---------------------------------------------------------------------------
extern "C" void kernel_launch(void* const* d_in, const int* in_sizes, int n_in,
                              void* d_out, int out_size, void* d_ws, size_t ws_size,
                              hipStream_t stream)
{
    const float* x  = (const float*)d_in[0];
    const float* Wq = (const float*)d_in[1];
    const float* Wk = (const float*)d_in[2];
    const float* Wv = (const float*)d_in[3];
    const float* Wo = (const float*)d_in[4];
    const float* bo = (const float*)d_in[5];
    float* out = (float*)d_out;

    const size_t mat = (size_t)MTOT * EMB;
    float* Qb = (float*)d_ws;
    float* Kb = Qb + mat;
    float* Vb = Kb + mat;

    const dim3 gemm_grid(EMB / 64, MTOT / 64);
    const dim3 gemm_blk(256);

    gemm_xwt<<<gemm_grid, gemm_blk, 0, stream>>>(x, Wq, Qb, nullptr, MTOT, EMB, EMB);
    gemm_xwt<<<gemm_grid, gemm_blk, 0, stream>>>(x, Wk, Kb, nullptr, MTOT, EMB, EMB);
    gemm_xwt<<<gemm_grid, gemm_blk, 0, stream>>>(x, Wv, Vb, nullptr, MTOT, EMB, EMB);

    attn_mfma<<<dim3(SEQ / 128, BATCH * HEADS), 256, 0, stream>>>(Qb, Kb, Vb, Qb);

    gemm_xwt<<<gemm_grid, gemm_blk, 0, stream>>>(Qb, Wo, out, bo, MTOT, EMB, EMB);
}

// Round 3
// 386.989 us; speedup vs baseline: 27.4352x; 4.3216x over previous
//
#include <hip/hip_runtime.h>
#include <math.h>

#define EMB   1024
#define HEADS 16
#define HD    64
#define SEQ   2048
#define BATCH 4
#define MTOT  (BATCH * SEQ)      // 8192 rows
#define XSZ   ((size_t)MTOT * EMB)   // 8388608
#define WSZ   ((size_t)EMB * EMB)    // 1048576

typedef __attribute__((ext_vector_type(8))) short s16x8;
typedef __attribute__((ext_vector_type(4))) short s16x4;
typedef __attribute__((ext_vector_type(4))) float f32x4;

#define LK_S 72
#define LV_S 72
#define LP_S 72

__device__ __forceinline__ short f2bf(float f) {
    unsigned u = __builtin_bit_cast(unsigned, f);
    u += 0x7fffu + ((u >> 16) & 1u);     // RNE
    return (short)(u >> 16);
}

__device__ __forceinline__ void async16(const void* g, void* l) {
    __builtin_amdgcn_global_load_lds(
        (const __attribute__((address_space(1))) unsigned*)g,
        (__attribute__((address_space(3))) unsigned*)l, 16, 0, 0);
}

// ---------------------------------------------------------------------------
// fp32 -> bf16 conversion of x and the four weight matrices.
// Wq is pre-scaled by 1/sqrt(HD)=0.125 so attention needs no score scaling.
// wcat rows: [0,1024)=Wq*0.125, [1024,2048)=Wk, [2048,3072)=Wv, [3072,4096)=Wo
// ---------------------------------------------------------------------------
__global__ __launch_bounds__(256)
void cvt_inputs(const float* __restrict__ x,  const float* __restrict__ wq,
                const float* __restrict__ wk, const float* __restrict__ wv,
                const float* __restrict__ wo, short* __restrict__ xb,
                short* __restrict__ wcat)
{
    const size_t e = ((size_t)blockIdx.x * 256 + threadIdx.x) * 8;
    const float* src;
    short* dst;
    float scale = 1.0f;
    if (e < XSZ) {
        src = x + e;
        dst = xb + e;
    } else {
        const size_t r = e - XSZ;
        const int w = (int)(r >> 20);            // WSZ = 2^20
        const size_t off = r & (WSZ - 1);
        src = (w == 0 ? wq : w == 1 ? wk : w == 2 ? wv : wo) + off;
        dst = wcat + r;
        if (w == 0) scale = 0.125f;
    }
    const float4 a = ((const float4*)src)[0];
    const float4 b = ((const float4*)src)[1];
    s16x8 v;
    v[0] = f2bf(a.x * scale); v[1] = f2bf(a.y * scale);
    v[2] = f2bf(a.z * scale); v[3] = f2bf(a.w * scale);
    v[4] = f2bf(b.x * scale); v[5] = f2bf(b.y * scale);
    v[6] = f2bf(b.z * scale); v[7] = f2bf(b.w * scale);
    *(s16x8*)dst = v;
}

// ---------------------------------------------------------------------------
// bf16 MFMA GEMM (m97 structure): C[m][n] = sum_k A[m][k]*B[n][k] (+bias)
// 128x128 block tile, BK=32, 256 threads = 4 waves each computing 64x64.
// Staging via global_load_lds width=16 (wave-uniform LDS base + lane*16):
// LDS layout is unpadded row-major [row][k], 64 B per row.
// OUT_BF16: C is bf16 (QKV path). else: C fp32 + bias (output projection).
// ---------------------------------------------------------------------------
template<bool OUT_BF16>
__global__ __launch_bounds__(256)
void gemm_bf16(const short* __restrict__ A, const short* __restrict__ B,
               void* __restrict__ C, int ldc, const float* __restrict__ bias,
               int K)
{
    __shared__ short lA[128 * 32];
    __shared__ short lB[128 * 32];

    const int tid  = threadIdx.x;
    const int wv   = tid >> 6;
    const int lane = tid & 63;
    const int col  = lane & 15;
    const int quad = lane >> 4;

    const int rowBase = blockIdx.y * 128;
    const int colBase = blockIdx.x * 128;

    // staging coords: 4 lanes per 64B row
    const int srow = tid >> 2;            // 0..63
    const int skO  = (tid & 3) * 8;       // k offset (elements)

    const short* gA = A + (size_t)(rowBase + srow) * K + skO;
    const short* gB = B + (size_t)(colBase + srow) * K + skO;

    const int m0 = (wv >> 1) * 64;
    const int n0 = (wv & 1) * 64;

    f32x4 acc[4][4];
#pragma unroll
    for (int i = 0; i < 4; ++i)
#pragma unroll
        for (int j = 0; j < 4; ++j) acc[i][j] = (f32x4){0.f, 0.f, 0.f, 0.f};

    for (int k0 = 0; k0 < K; k0 += 32) {
        async16(gA + k0,                 (char*)lA + wv * 1024);
        async16(gA + k0 + (size_t)64 * K, (char*)lA + 4096 + wv * 1024);
        async16(gB + k0,                 (char*)lB + wv * 1024);
        async16(gB + k0 + (size_t)64 * K, (char*)lB + 4096 + wv * 1024);
        __syncthreads();   // drains vmcnt before barrier (compiler-enforced)

        s16x8 af[4], bf[4];
#pragma unroll
        for (int i = 0; i < 4; ++i)
            af[i] = *(const s16x8*)&lA[(m0 + i * 16 + col) * 32 + quad * 8];
#pragma unroll
        for (int j = 0; j < 4; ++j)
            bf[j] = *(const s16x8*)&lB[(n0 + j * 16 + col) * 32 + quad * 8];
#pragma unroll
        for (int i = 0; i < 4; ++i)
#pragma unroll
            for (int j = 0; j < 4; ++j)
                acc[i][j] = __builtin_amdgcn_mfma_f32_16x16x32_bf16(af[i], bf[j], acc[i][j], 0, 0, 0);
        __syncthreads();   // protect LDS for next staging round
    }

    // epilogue: D row = quad*4+r (m), col = lane&15 (n)
    if (OUT_BF16) {
        short* Cb = (short*)C;
#pragma unroll
        for (int i = 0; i < 4; ++i) {
            const int rg = rowBase + m0 + i * 16 + quad * 4;
#pragma unroll
            for (int j = 0; j < 4; ++j) {
                const int cg = colBase + n0 + j * 16 + col;
#pragma unroll
                for (int r = 0; r < 4; ++r)
                    Cb[(size_t)(rg + r) * ldc + cg] = f2bf(acc[i][j][r]);
            }
        }
    } else {
        float* Cf = (float*)C;
#pragma unroll
        for (int j = 0; j < 4; ++j) {
            const int cg = colBase + n0 + j * 16 + col;
            const float bj = bias ? bias[cg] : 0.f;
#pragma unroll
            for (int i = 0; i < 4; ++i) {
                const int rg = rowBase + m0 + i * 16 + quad * 4;
#pragma unroll
                for (int r = 0; r < 4; ++r)
                    Cf[(size_t)(rg + r) * ldc + cg] = acc[i][j][r] + bj;
            }
        }
    }
}

// ---------------------------------------------------------------------------
// Flash-style causal attention, bf16 in / bf16 out.
// QKV is the fused projection output: row m = b*SEQ+s, cols [0,1024)=Q,
// [1024,2048)=K, [2048,3072)=V; row stride 3072. Q is pre-scaled by 0.125.
// O is written bf16 row-major 8192x1024 (feeds the O-projection GEMM).
// ---------------------------------------------------------------------------
#define LDQ 3072
__global__ __launch_bounds__(256)
void attn_mfma(const short* __restrict__ QKV, short* __restrict__ O)
{
    __shared__ short lK[64 * LK_S];       // lK[key][hd]
    __shared__ short lV[64 * LV_S];       // lV[hd][key]  (transposed)
    __shared__ short lP[8 * 16 * LP_S];   // per (wave,rb): lP[q][key]

    const int tid  = threadIdx.x;
    const int wv   = tid >> 6;
    const int lane = tid & 63;
    const int col  = lane & 15;
    const int quad = lane >> 4;

    const int qb = blockIdx.x * 128;
    const int bh = blockIdx.y;
    const int b  = bh >> 4;
    const int h  = bh & 15;
    const size_t baseq = (size_t)b * SEQ * LDQ + (size_t)h * HD;
    const size_t basek = baseq + 1024;
    const size_t basev = baseq + 2048;
    const size_t baseo = (size_t)b * SEQ * EMB + (size_t)h * HD;

    // Q fragments (B-operand: n=col -> query, k=quad*8+j). Already scaled.
    s16x8 qf[2][2];
#pragma unroll
    for (int rb = 0; rb < 2; ++rb) {
        const short* qr = QKV + baseq + (size_t)(qb + wv * 32 + rb * 16 + col) * LDQ;
#pragma unroll
        for (int c = 0; c < 2; ++c)
            qf[rb][c] = *(const s16x8*)(qr + c * 32 + quad * 8);
    }

    float mrow[2] = {-3.0e38f, -3.0e38f};
    float lrow[2] = {0.f, 0.f};
    f32x4 of[2][4];
#pragma unroll
    for (int rb = 0; rb < 2; ++rb)
#pragma unroll
        for (int u = 0; u < 4; ++u) of[rb][u] = (f32x4){0.f, 0.f, 0.f, 0.f};

    const int nt = qb / 64 + 2;

    for (int kt = 0; kt < nt; ++kt) {
        const int kb = kt * 64;
        __syncthreads();
        // ---- stage K (row-major) and V (transposed) ----
        {
            const int r  = tid >> 2;             // key 0..63
            const int c0 = (tid & 3) * 16;       // dim offset
            const short* kr = QKV + basek + (size_t)(kb + r) * LDQ + c0;
            const short* vr = QKV + basev + (size_t)(kb + r) * LDQ + c0;
            *(s16x8*)&lK[r * LK_S + c0]     = *(const s16x8*)(kr);
            *(s16x8*)&lK[r * LK_S + c0 + 8] = *(const s16x8*)(kr + 8);
            const s16x8 v0 = *(const s16x8*)(vr);
            const s16x8 v1 = *(const s16x8*)(vr + 8);
#pragma unroll
            for (int t = 0; t < 8; ++t) {
                lV[(c0 + t) * LV_S + r]     = v0[t];
                lV[(c0 + 8 + t) * LV_S + r] = v1[t];
            }
        }
        __syncthreads();

        // ---- S^T = K·Q^T : C/D row = key(quad*4+reg), col = query ----
        f32x4 s[2][4];
#pragma unroll
        for (int t = 0; t < 4; ++t) {
            const s16x8 kf0 = *(const s16x8*)&lK[(t * 16 + col) * LK_S + quad * 8];
            const s16x8 kf1 = *(const s16x8*)&lK[(t * 16 + col) * LK_S + 32 + quad * 8];
#pragma unroll
            for (int rb = 0; rb < 2; ++rb) {
                f32x4 acc = (f32x4){0.f, 0.f, 0.f, 0.f};
                acc = __builtin_amdgcn_mfma_f32_16x16x32_bf16(kf0, qf[rb][0], acc, 0, 0, 0);
                acc = __builtin_amdgcn_mfma_f32_16x16x32_bf16(kf1, qf[rb][1], acc, 0, 0, 0);
                s[rb][t] = acc;
            }
        }

#pragma unroll
        for (int rb = 0; rb < 2; ++rb) {
            const int qlo = qb + wv * 32 + rb * 16;
            if (kb > qlo + 15) continue;          // fully masked for this rb
            const int qg = qlo + col;

            if (kb + 63 > qlo) {                  // diagonal tile: causal mask
#pragma unroll
                for (int t = 0; t < 4; ++t)
#pragma unroll
                    for (int r = 0; r < 4; ++r) {
                        const int kg = kb + t * 16 + quad * 4 + r;
                        if (kg > qg) s[rb][t][r] = -3.0e38f;
                    }
            }

            float mx = s[rb][0][0];
#pragma unroll
            for (int t = 0; t < 4; ++t)
#pragma unroll
                for (int r = 0; r < 4; ++r) mx = fmaxf(mx, s[rb][t][r]);
            mx = fmaxf(mx, __shfl_xor(mx, 16, 64));
            mx = fmaxf(mx, __shfl_xor(mx, 32, 64));
            const float mnew = fmaxf(mrow[rb], mx);

            float sum = 0.f;
#pragma unroll
            for (int t = 0; t < 4; ++t)
#pragma unroll
                for (int r = 0; r < 4; ++r) {
                    const float p = __expf(s[rb][t][r] - mnew);
                    s[rb][t][r] = p;
                    sum += p;
                }
            sum += __shfl_xor(sum, 16, 64);
            sum += __shfl_xor(sum, 32, 64);

            const float alpha = __expf(mrow[rb] - mnew);
            lrow[rb] = lrow[rb] * alpha + sum;
            mrow[rb] = mnew;

            short* pbase = &lP[((wv * 2 + rb) * 16) * LP_S];
#pragma unroll
            for (int t = 0; t < 4; ++t) {
                s16x4 pk;
                pk[0] = f2bf(s[rb][t][0]); pk[1] = f2bf(s[rb][t][1]);
                pk[2] = f2bf(s[rb][t][2]); pk[3] = f2bf(s[rb][t][3]);
                *(s16x4*)&pbase[col * LP_S + t * 16 + quad * 4] = pk;
            }

            const float a0 = __shfl(alpha, quad * 4 + 0, 64);
            const float a1 = __shfl(alpha, quad * 4 + 1, 64);
            const float a2 = __shfl(alpha, quad * 4 + 2, 64);
            const float a3 = __shfl(alpha, quad * 4 + 3, 64);
#pragma unroll
            for (int u = 0; u < 4; ++u) {
                of[rb][u][0] *= a0; of[rb][u][1] *= a1;
                of[rb][u][2] *= a2; of[rb][u][3] *= a3;
            }

#pragma unroll
            for (int c = 0; c < 2; ++c) {
                const s16x8 pa = *(const s16x8*)&pbase[col * LP_S + c * 32 + quad * 8];
#pragma unroll
                for (int u = 0; u < 4; ++u) {
                    const s16x8 vf = *(const s16x8*)&lV[(u * 16 + col) * LV_S + c * 32 + quad * 8];
                    of[rb][u] = __builtin_amdgcn_mfma_f32_16x16x32_bf16(pa, vf, of[rb][u], 0, 0, 0);
                }
            }
        }
    }

    // ---- epilogue: normalize and store bf16 ----
#pragma unroll
    for (int rb = 0; rb < 2; ++rb) {
        const float rl = 1.f / lrow[rb];
        const float r0 = __shfl(rl, quad * 4 + 0, 64);
        const float r1 = __shfl(rl, quad * 4 + 1, 64);
        const float r2 = __shfl(rl, quad * 4 + 2, 64);
        const float r3 = __shfl(rl, quad * 4 + 3, 64);
        const int q0 = qb + wv * 32 + rb * 16 + quad * 4;
        short* o0 = O + baseo + (size_t)(q0 + 0) * EMB;
        short* o1 = O + baseo + (size_t)(q0 + 1) * EMB;
        short* o2 = O + baseo + (size_t)(q0 + 2) * EMB;
        short* o3 = O + baseo + (size_t)(q0 + 3) * EMB;
#pragma unroll
        for (int u = 0; u < 4; ++u) {
            o0[u * 16 + col] = f2bf(of[rb][u][0] * r0);
            o1[u * 16 + col] = f2bf(of[rb][u][1] * r1);
            o2[u * 16 + col] = f2bf(of[rb][u][2] * r2);
            o3[u * 16 + col] = f2bf(of[rb][u][3] * r3);
        }
    }
}

// ---------------------------------------------------------------------------
extern "C" void kernel_launch(void* const* d_in, const int* in_sizes, int n_in,
                              void* d_out, int out_size, void* d_ws, size_t ws_size,
                              hipStream_t stream)
{
    const float* x  = (const float*)d_in[0];
    const float* Wq = (const float*)d_in[1];
    const float* Wk = (const float*)d_in[2];
    const float* Wv = (const float*)d_in[3];
    const float* Wo = (const float*)d_in[4];
    const float* bo = (const float*)d_in[5];
    float* out = (float*)d_out;

    short* xb   = (short*)d_ws;                  // 16 MiB
    short* wcat = xb + XSZ;                      //  8 MiB
    short* qkv  = wcat + 4 * WSZ;                // 48 MiB
    short* ob   = qkv + (size_t)MTOT * 3 * EMB;  // 16 MiB  (total 88 MiB)

    // convert inputs to bf16 (Wq pre-scaled by 0.125)
    const int cvt_blocks = (int)((XSZ + 4 * WSZ) / 8 / 256);   // 6144
    cvt_inputs<<<cvt_blocks, 256, 0, stream>>>(x, Wq, Wk, Wv, Wo, xb, wcat);

    // fused QKV projection: [8192,1024] @ [3072,1024]^T -> bf16 [8192,3072]
    gemm_bf16<true><<<dim3(3072 / 128, MTOT / 128), 256, 0, stream>>>(
        xb, wcat, qkv, 3072, nullptr, EMB);

    // attention: bf16 in (stride 3072), bf16 out (stride 1024)
    attn_mfma<<<dim3(SEQ / 128, BATCH * HEADS), 256, 0, stream>>>(qkv, ob);

    // output projection: [8192,1024] @ [1024,1024]^T + bias -> fp32 d_out
    gemm_bf16<false><<<dim3(EMB / 128, MTOT / 128), 256, 0, stream>>>(
        ob, wcat + (size_t)3 * WSZ, out, EMB, bo, EMB);
}

// Round 4
// 294.551 us; speedup vs baseline: 36.0451x; 1.3138x over previous
//
#include <hip/hip_runtime.h>
#include <math.h>

#define EMB   1024
#define HEADS 16
#define HD    64
#define SEQ   2048
#define BATCH 4
#define MTOT  (BATCH * SEQ)      // 8192 rows
#define XSZ   ((size_t)MTOT * EMB)   // 8388608
#define WSZ   ((size_t)EMB * EMB)    // 1048576

typedef __attribute__((ext_vector_type(8))) short s16x8;
typedef __attribute__((ext_vector_type(4))) short s16x4;
typedef __attribute__((ext_vector_type(4))) float f32x4;

#define LK_S 72
#define LV_S 72
#define LP_S 72

__device__ __forceinline__ short f2bf(float f) {
    unsigned u = __builtin_bit_cast(unsigned, f);
    u += 0x7fffu + ((u >> 16) & 1u);     // RNE
    return (short)(u >> 16);
}

__device__ __forceinline__ void async16(const void* g, void* l) {
    __builtin_amdgcn_global_load_lds(
        (const __attribute__((address_space(1))) unsigned*)g,
        (__attribute__((address_space(3))) unsigned*)l, 16, 0, 0);
}

// ---------------------------------------------------------------------------
// fp32 -> bf16 conversion of x and the four weight matrices.
// Wq is pre-scaled by 1/sqrt(HD)=0.125 so attention needs no score scaling.
// ---------------------------------------------------------------------------
__global__ __launch_bounds__(256)
void cvt_inputs(const float* __restrict__ x,  const float* __restrict__ wq,
                const float* __restrict__ wk, const float* __restrict__ wv,
                const float* __restrict__ wo, short* __restrict__ xb,
                short* __restrict__ wcat)
{
    const size_t e = ((size_t)blockIdx.x * 256 + threadIdx.x) * 8;
    const float* src;
    short* dst;
    float scale = 1.0f;
    if (e < XSZ) {
        src = x + e;
        dst = xb + e;
    } else {
        const size_t r = e - XSZ;
        const int w = (int)(r >> 20);            // WSZ = 2^20
        const size_t off = r & (WSZ - 1);
        src = (w == 0 ? wq : w == 1 ? wk : w == 2 ? wv : wo) + off;
        dst = wcat + r;
        if (w == 0) scale = 0.125f;
    }
    const float4 a = ((const float4*)src)[0];
    const float4 b = ((const float4*)src)[1];
    s16x8 v;
    v[0] = f2bf(a.x * scale); v[1] = f2bf(a.y * scale);
    v[2] = f2bf(a.z * scale); v[3] = f2bf(a.w * scale);
    v[4] = f2bf(b.x * scale); v[5] = f2bf(b.y * scale);
    v[6] = f2bf(b.z * scale); v[7] = f2bf(b.w * scale);
    *(s16x8*)dst = v;
}

// ---------------------------------------------------------------------------
// bf16 MFMA GEMM (m97 structure): C[m][n] = sum_k A[m][k]*B[n][k] (+bias)
// ---------------------------------------------------------------------------
template<bool OUT_BF16>
__global__ __launch_bounds__(256)
void gemm_bf16(const short* __restrict__ A, const short* __restrict__ B,
               void* __restrict__ C, int ldc, const float* __restrict__ bias,
               int K)
{
    __shared__ short lA[128 * 32];
    __shared__ short lB[128 * 32];

    const int tid  = threadIdx.x;
    const int wv   = tid >> 6;
    const int lane = tid & 63;
    const int col  = lane & 15;
    const int quad = lane >> 4;

    const int rowBase = blockIdx.y * 128;
    const int colBase = blockIdx.x * 128;

    const int srow = tid >> 2;
    const int skO  = (tid & 3) * 8;

    const short* gA = A + (size_t)(rowBase + srow) * K + skO;
    const short* gB = B + (size_t)(colBase + srow) * K + skO;

    const int m0 = (wv >> 1) * 64;
    const int n0 = (wv & 1) * 64;

    f32x4 acc[4][4];
#pragma unroll
    for (int i = 0; i < 4; ++i)
#pragma unroll
        for (int j = 0; j < 4; ++j) acc[i][j] = (f32x4){0.f, 0.f, 0.f, 0.f};

    for (int k0 = 0; k0 < K; k0 += 32) {
        async16(gA + k0,                 (char*)lA + wv * 1024);
        async16(gA + k0 + (size_t)64 * K, (char*)lA + 4096 + wv * 1024);
        async16(gB + k0,                 (char*)lB + wv * 1024);
        async16(gB + k0 + (size_t)64 * K, (char*)lB + 4096 + wv * 1024);
        __syncthreads();

        s16x8 af[4], bf[4];
#pragma unroll
        for (int i = 0; i < 4; ++i)
            af[i] = *(const s16x8*)&lA[(m0 + i * 16 + col) * 32 + quad * 8];
#pragma unroll
        for (int j = 0; j < 4; ++j)
            bf[j] = *(const s16x8*)&lB[(n0 + j * 16 + col) * 32 + quad * 8];
#pragma unroll
        for (int i = 0; i < 4; ++i)
#pragma unroll
            for (int j = 0; j < 4; ++j)
                acc[i][j] = __builtin_amdgcn_mfma_f32_16x16x32_bf16(af[i], bf[j], acc[i][j], 0, 0, 0);
        __syncthreads();
    }

    if (OUT_BF16) {
        short* Cb = (short*)C;
#pragma unroll
        for (int i = 0; i < 4; ++i) {
            const int rg = rowBase + m0 + i * 16 + quad * 4;
#pragma unroll
            for (int j = 0; j < 4; ++j) {
                const int cg = colBase + n0 + j * 16 + col;
#pragma unroll
                for (int r = 0; r < 4; ++r)
                    Cb[(size_t)(rg + r) * ldc + cg] = f2bf(acc[i][j][r]);
            }
        }
    } else {
        float* Cf = (float*)C;
#pragma unroll
        for (int j = 0; j < 4; ++j) {
            const int cg = colBase + n0 + j * 16 + col;
            const float bj = bias ? bias[cg] : 0.f;
#pragma unroll
            for (int i = 0; i < 4; ++i) {
                const int rg = rowBase + m0 + i * 16 + quad * 4;
#pragma unroll
                for (int r = 0; r < 4; ++r)
                    Cf[(size_t)(rg + r) * ldc + cg] = acc[i][j][r] + bj;
            }
        }
    }
}

// ---------------------------------------------------------------------------
// Flash-style causal attention, bf16 in / bf16 out.
// Grid (8, 64): each block processes query tiles x and 15-x of one (b,h)
// sequentially -> every block does exactly 34 key-tiles (uniform work).
// Register prefetch double-buffers the K/V staging; QK MFMAs are skipped for
// fully-masked row-blocks; lP is per-wave (rb processed sequentially).
// ---------------------------------------------------------------------------
#define LDQ 3072
__global__ __launch_bounds__(256)
void attn_mfma(const short* __restrict__ QKV, short* __restrict__ O)
{
    __shared__ short lK[64 * LK_S];       // lK[key][hd]
    __shared__ short lV[64 * LV_S];       // lV[hd][key]  (transposed)
    __shared__ short lP[4 * 16 * LP_S];   // per wave: lP[q][key]

    const int tid  = threadIdx.x;
    const int wv   = tid >> 6;
    const int lane = tid & 63;
    const int col  = lane & 15;
    const int quad = lane >> 4;

    const int bh = blockIdx.y;
    const int b  = bh >> 4;
    const int h  = bh & 15;
    const size_t baseq = (size_t)b * SEQ * LDQ + (size_t)h * HD;
    const size_t basek = baseq + 1024;
    const size_t basev = baseq + 2048;
    const size_t baseo = (size_t)b * SEQ * EMB + (size_t)h * HD;

    // staging coords
    const int r  = tid >> 2;             // key 0..63
    const int c0 = (tid & 3) * 16;       // dim offset

    short* pbase = &lP[(wv * 16) * LP_S];

    for (int half = 0; half < 2; ++half) {
        const int qtile = half ? (15 - (int)blockIdx.x) : (int)blockIdx.x;
        const int qb = qtile * 128;
        const int qlo_w = qb + wv * 32;

        // Q fragments (B-operand: n=col -> query, k=quad*8+j). Pre-scaled.
        s16x8 qf[2][2];
#pragma unroll
        for (int rb = 0; rb < 2; ++rb) {
            const short* qr = QKV + baseq + (size_t)(qlo_w + rb * 16 + col) * LDQ;
#pragma unroll
            for (int c = 0; c < 2; ++c)
                qf[rb][c] = *(const s16x8*)(qr + c * 32 + quad * 8);
        }

        float mrow[2] = {-3.0e38f, -3.0e38f};
        float lrow[2] = {0.f, 0.f};
        f32x4 of[2][4];
#pragma unroll
        for (int rb = 0; rb < 2; ++rb)
#pragma unroll
            for (int u = 0; u < 4; ++u) of[rb][u] = (f32x4){0.f, 0.f, 0.f, 0.f};

        const int nt = qb / 64 + 2;

        // prefetch tile 0 into registers
        const short* kr = QKV + basek + (size_t)r * LDQ + c0;
        const short* vr = QKV + basev + (size_t)r * LDQ + c0;
        s16x8 pk0 = *(const s16x8*)(kr);
        s16x8 pk1 = *(const s16x8*)(kr + 8);
        s16x8 pv0 = *(const s16x8*)(vr);
        s16x8 pv1 = *(const s16x8*)(vr + 8);

        for (int kt = 0; kt < nt; ++kt) {
            const int kb = kt * 64;
            __syncthreads();                     // LDS free from prev compute
            // ---- write staged regs to LDS ----
            *(s16x8*)&lK[r * LK_S + c0]     = pk0;
            *(s16x8*)&lK[r * LK_S + c0 + 8] = pk1;
#pragma unroll
            for (int t = 0; t < 8; ++t) {
                lV[(c0 + t) * LV_S + r]     = pv0[t];
                lV[(c0 + 8 + t) * LV_S + r] = pv1[t];
            }
            __syncthreads();

            // ---- prefetch next tile (overlaps with compute below) ----
            if (kt + 1 < nt) {
                const short* krn = QKV + basek + (size_t)(kb + 64 + r) * LDQ + c0;
                const short* vrn = QKV + basev + (size_t)(kb + 64 + r) * LDQ + c0;
                pk0 = *(const s16x8*)(krn);
                pk1 = *(const s16x8*)(krn + 8);
                pv0 = *(const s16x8*)(vrn);
                pv1 = *(const s16x8*)(vrn + 8);
            }

            if (kb > qlo_w + 31) continue;       // both rbs masked for this wave

            // K fragments (shared by both rbs)
            s16x8 kf[4][2];
#pragma unroll
            for (int t = 0; t < 4; ++t) {
                kf[t][0] = *(const s16x8*)&lK[(t * 16 + col) * LK_S + quad * 8];
                kf[t][1] = *(const s16x8*)&lK[(t * 16 + col) * LK_S + 32 + quad * 8];
            }

#pragma unroll
            for (int rb = 0; rb < 2; ++rb) {
                const int qlo = qlo_w + rb * 16;
                if (kb > qlo + 15) continue;      // this rb fully masked
                const int qg = qlo + col;

                // S^T = K·Q^T : C/D row = key(quad*4+reg), col = query
                f32x4 s[4];
#pragma unroll
                for (int t = 0; t < 4; ++t) {
                    f32x4 acc = (f32x4){0.f, 0.f, 0.f, 0.f};
                    acc = __builtin_amdgcn_mfma_f32_16x16x32_bf16(kf[t][0], qf[rb][0], acc, 0, 0, 0);
                    acc = __builtin_amdgcn_mfma_f32_16x16x32_bf16(kf[t][1], qf[rb][1], acc, 0, 0, 0);
                    s[t] = acc;
                }

                if (kb + 63 > qlo) {              // diagonal tile: causal mask
#pragma unroll
                    for (int t = 0; t < 4; ++t)
#pragma unroll
                        for (int rr = 0; rr < 4; ++rr) {
                            const int kg = kb + t * 16 + quad * 4 + rr;
                            if (kg > qg) s[t][rr] = -3.0e38f;
                        }
                }

                float mx = s[0][0];
#pragma unroll
                for (int t = 0; t < 4; ++t)
#pragma unroll
                    for (int rr = 0; rr < 4; ++rr) mx = fmaxf(mx, s[t][rr]);
                mx = fmaxf(mx, __shfl_xor(mx, 16, 64));
                mx = fmaxf(mx, __shfl_xor(mx, 32, 64));
                const float mnew = fmaxf(mrow[rb], mx);

                float sum = 0.f;
#pragma unroll
                for (int t = 0; t < 4; ++t)
#pragma unroll
                    for (int rr = 0; rr < 4; ++rr) {
                        const float p = __expf(s[t][rr] - mnew);
                        s[t][rr] = p;
                        sum += p;
                    }
                sum += __shfl_xor(sum, 16, 64);
                sum += __shfl_xor(sum, 32, 64);

                const float alpha = __expf(mrow[rb] - mnew);
                lrow[rb] = lrow[rb] * alpha + sum;
                mrow[rb] = mnew;

                // pack P (bf16) into per-wave A-operand staging: lP[q][key]
#pragma unroll
                for (int t = 0; t < 4; ++t) {
                    s16x4 pk;
                    pk[0] = f2bf(s[t][0]); pk[1] = f2bf(s[t][1]);
                    pk[2] = f2bf(s[t][2]); pk[3] = f2bf(s[t][3]);
                    *(s16x4*)&pbase[col * LP_S + t * 16 + quad * 4] = pk;
                }

                const float a0 = __shfl(alpha, quad * 4 + 0, 64);
                const float a1 = __shfl(alpha, quad * 4 + 1, 64);
                const float a2 = __shfl(alpha, quad * 4 + 2, 64);
                const float a3 = __shfl(alpha, quad * 4 + 3, 64);
#pragma unroll
                for (int u = 0; u < 4; ++u) {
                    of[rb][u][0] *= a0; of[rb][u][1] *= a1;
                    of[rb][u][2] *= a2; of[rb][u][3] *= a3;
                }

#pragma unroll
                for (int c = 0; c < 2; ++c) {
                    const s16x8 pa = *(const s16x8*)&pbase[col * LP_S + c * 32 + quad * 8];
#pragma unroll
                    for (int u = 0; u < 4; ++u) {
                        const s16x8 vf = *(const s16x8*)&lV[(u * 16 + col) * LV_S + c * 32 + quad * 8];
                        of[rb][u] = __builtin_amdgcn_mfma_f32_16x16x32_bf16(pa, vf, of[rb][u], 0, 0, 0);
                    }
                }
            }
        }

        // ---- epilogue: normalize and store bf16 ----
#pragma unroll
        for (int rb = 0; rb < 2; ++rb) {
            const float rl = 1.f / lrow[rb];
            const float r0 = __shfl(rl, quad * 4 + 0, 64);
            const float r1 = __shfl(rl, quad * 4 + 1, 64);
            const float r2 = __shfl(rl, quad * 4 + 2, 64);
            const float r3 = __shfl(rl, quad * 4 + 3, 64);
            const int q0 = qlo_w + rb * 16 + quad * 4;
            short* o0 = O + baseo + (size_t)(q0 + 0) * EMB;
            short* o1 = O + baseo + (size_t)(q0 + 1) * EMB;
            short* o2 = O + baseo + (size_t)(q0 + 2) * EMB;
            short* o3 = O + baseo + (size_t)(q0 + 3) * EMB;
#pragma unroll
            for (int u = 0; u < 4; ++u) {
                o0[u * 16 + col] = f2bf(of[rb][u][0] * r0);
                o1[u * 16 + col] = f2bf(of[rb][u][1] * r1);
                o2[u * 16 + col] = f2bf(of[rb][u][2] * r2);
                o3[u * 16 + col] = f2bf(of[rb][u][3] * r3);
            }
        }
    }
}

// ---------------------------------------------------------------------------
extern "C" void kernel_launch(void* const* d_in, const int* in_sizes, int n_in,
                              void* d_out, int out_size, void* d_ws, size_t ws_size,
                              hipStream_t stream)
{
    const float* x  = (const float*)d_in[0];
    const float* Wq = (const float*)d_in[1];
    const float* Wk = (const float*)d_in[2];
    const float* Wv = (const float*)d_in[3];
    const float* Wo = (const float*)d_in[4];
    const float* bo = (const float*)d_in[5];
    float* out = (float*)d_out;

    short* xb   = (short*)d_ws;                  // 16 MiB
    short* wcat = xb + XSZ;                      //  8 MiB
    short* qkv  = wcat + 4 * WSZ;                // 48 MiB
    short* ob   = qkv + (size_t)MTOT * 3 * EMB;  // 16 MiB

    const int cvt_blocks = (int)((XSZ + 4 * WSZ) / 8 / 256);   // 6144
    cvt_inputs<<<cvt_blocks, 256, 0, stream>>>(x, Wq, Wk, Wv, Wo, xb, wcat);

    gemm_bf16<true><<<dim3(3072 / 128, MTOT / 128), 256, 0, stream>>>(
        xb, wcat, qkv, 3072, nullptr, EMB);

    attn_mfma<<<dim3(8, BATCH * HEADS), 256, 0, stream>>>(qkv, ob);

    gemm_bf16<false><<<dim3(EMB / 128, MTOT / 128), 256, 0, stream>>>(
        ob, wcat + (size_t)3 * WSZ, out, EMB, bo, EMB);
}

// Round 5
// 280.418 us; speedup vs baseline: 37.8618x; 1.0504x over previous
//
#include <hip/hip_runtime.h>
#include <math.h>

#define EMB   1024
#define HEADS 16
#define HD    64
#define SEQ   2048
#define BATCH 4
#define MTOT  (BATCH * SEQ)      // 8192 rows
#define XSZ   ((size_t)MTOT * EMB)   // 8388608
#define WSZ   ((size_t)EMB * EMB)    // 1048576

typedef __attribute__((ext_vector_type(8))) short s16x8;
typedef __attribute__((ext_vector_type(4))) short s16x4;
typedef __attribute__((ext_vector_type(4))) float f32x4;

__device__ __forceinline__ short f2bf(float f) {
    unsigned u = __builtin_bit_cast(unsigned, f);
    u += 0x7fffu + ((u >> 16) & 1u);     // RNE
    return (short)(u >> 16);
}

// packed f32x2 -> bf16x2 (low = a, high = b). HW v_cvt_pk_bf16_f32 if present.
__device__ __forceinline__ unsigned pk_bf16(float a, float b) {
#if __has_builtin(__builtin_amdgcn_cvt_pk_bf16_f32)
    typedef __attribute__((ext_vector_type(2))) __bf16 bf16x2;
    return __builtin_bit_cast(unsigned, __builtin_amdgcn_cvt_pk_bf16_f32(a, b));
#else
    return (unsigned)(unsigned short)f2bf(a) |
           ((unsigned)(unsigned short)f2bf(b) << 16);
#endif
}

__device__ __forceinline__ void async16(const void* g, void* l) {
    __builtin_amdgcn_global_load_lds(
        (const __attribute__((address_space(1))) unsigned*)g,
        (__attribute__((address_space(3))) unsigned*)l, 16, 0, 0);
}

// ---------------------------------------------------------------------------
// fp32 -> bf16 conversion of x and the four weight matrices.
// Wq is pre-scaled by 1/sqrt(HD)=0.125 so attention needs no score scaling.
// ---------------------------------------------------------------------------
__global__ __launch_bounds__(256)
void cvt_inputs(const float* __restrict__ x,  const float* __restrict__ wq,
                const float* __restrict__ wk, const float* __restrict__ wv,
                const float* __restrict__ wo, short* __restrict__ xb,
                short* __restrict__ wcat)
{
    const size_t e = ((size_t)blockIdx.x * 256 + threadIdx.x) * 8;
    const float* src;
    short* dst;
    float scale = 1.0f;
    if (e < XSZ) {
        src = x + e;
        dst = xb + e;
    } else {
        const size_t r = e - XSZ;
        const int w = (int)(r >> 20);            // WSZ = 2^20
        const size_t off = r & (WSZ - 1);
        src = (w == 0 ? wq : w == 1 ? wk : w == 2 ? wv : wo) + off;
        dst = wcat + r;
        if (w == 0) scale = 0.125f;
    }
    const float4 a = ((const float4*)src)[0];
    const float4 b = ((const float4*)src)[1];
    s16x8 v;
    v[0] = f2bf(a.x * scale); v[1] = f2bf(a.y * scale);
    v[2] = f2bf(a.z * scale); v[3] = f2bf(a.w * scale);
    v[4] = f2bf(b.x * scale); v[5] = f2bf(b.y * scale);
    v[6] = f2bf(b.z * scale); v[7] = f2bf(b.w * scale);
    *(s16x8*)dst = v;
}

// ---------------------------------------------------------------------------
// bf16 MFMA GEMM (m97 structure): C[m][n] = sum_k A[m][k]*B[n][k] (+bias)
// ---------------------------------------------------------------------------
template<bool OUT_BF16>
__global__ __launch_bounds__(256)
void gemm_bf16(const short* __restrict__ A, const short* __restrict__ B,
               void* __restrict__ C, int ldc, const float* __restrict__ bias,
               int K)
{
    __shared__ short lA[128 * 32];
    __shared__ short lB[128 * 32];

    const int tid  = threadIdx.x;
    const int wv   = tid >> 6;
    const int lane = tid & 63;
    const int col  = lane & 15;
    const int quad = lane >> 4;

    const int rowBase = blockIdx.y * 128;
    const int colBase = blockIdx.x * 128;

    const int srow = tid >> 2;
    const int skO  = (tid & 3) * 8;

    const short* gA = A + (size_t)(rowBase + srow) * K + skO;
    const short* gB = B + (size_t)(colBase + srow) * K + skO;

    const int m0 = (wv >> 1) * 64;
    const int n0 = (wv & 1) * 64;

    f32x4 acc[4][4];
#pragma unroll
    for (int i = 0; i < 4; ++i)
#pragma unroll
        for (int j = 0; j < 4; ++j) acc[i][j] = (f32x4){0.f, 0.f, 0.f, 0.f};

    for (int k0 = 0; k0 < K; k0 += 32) {
        async16(gA + k0,                 (char*)lA + wv * 1024);
        async16(gA + k0 + (size_t)64 * K, (char*)lA + 4096 + wv * 1024);
        async16(gB + k0,                 (char*)lB + wv * 1024);
        async16(gB + k0 + (size_t)64 * K, (char*)lB + 4096 + wv * 1024);
        __syncthreads();

        s16x8 af[4], bf[4];
#pragma unroll
        for (int i = 0; i < 4; ++i)
            af[i] = *(const s16x8*)&lA[(m0 + i * 16 + col) * 32 + quad * 8];
#pragma unroll
        for (int j = 0; j < 4; ++j)
            bf[j] = *(const s16x8*)&lB[(n0 + j * 16 + col) * 32 + quad * 8];
#pragma unroll
        for (int i = 0; i < 4; ++i)
#pragma unroll
            for (int j = 0; j < 4; ++j)
                acc[i][j] = __builtin_amdgcn_mfma_f32_16x16x32_bf16(af[i], bf[j], acc[i][j], 0, 0, 0);
        __syncthreads();
    }

    if (OUT_BF16) {
        short* Cb = (short*)C;
#pragma unroll
        for (int i = 0; i < 4; ++i) {
            const int rg = rowBase + m0 + i * 16 + quad * 4;
#pragma unroll
            for (int j = 0; j < 4; ++j) {
                const int cg = colBase + n0 + j * 16 + col;
#pragma unroll
                for (int r = 0; r < 4; ++r)
                    Cb[(size_t)(rg + r) * ldc + cg] = f2bf(acc[i][j][r]);
            }
        }
    } else {
        float* Cf = (float*)C;
#pragma unroll
        for (int j = 0; j < 4; ++j) {
            const int cg = colBase + n0 + j * 16 + col;
            const float bj = bias ? bias[cg] : 0.f;
#pragma unroll
            for (int i = 0; i < 4; ++i) {
                const int rg = rowBase + m0 + i * 16 + quad * 4;
#pragma unroll
                for (int r = 0; r < 4; ++r)
                    Cf[(size_t)(rg + r) * ldc + cg] = acc[i][j][r] + bj;
            }
        }
    }
}

// ---------------------------------------------------------------------------
// Flash-style causal attention, bf16 in / bf16 out. 512 threads = 8 waves,
// 16 queries per wave, 128 queries per block. Grid (8,64): block processes
// query tiles x and 15-x (uniform 34 key-tiles).
//  - lV transpose staged with wave-uniform d (conflict-free: key = lane).
//  - PV computes O^T = mfma(V^T, P): softmax state, alpha rescale and
//    normalize are per-lane (query = lane&15) -> zero shuffle broadcasts.
//  - packed bf16 converts via v_cvt_pk_bf16_f32 when available.
// ---------------------------------------------------------------------------
#define LDQ 3072
__global__ __launch_bounds__(512)
void attn_mfma(const short* __restrict__ QKV, short* __restrict__ O)
{
    __shared__ short lK[64 * 72];        // [key][d]
    __shared__ short lV[64 * 72];        // [d][key]  (transposed)
    __shared__ short lP[8 * 16 * 72];    // per wave: [q][key]

    const int tid  = threadIdx.x;
    const int wv   = tid >> 6;           // 0..7
    const int lane = tid & 63;
    const int col  = lane & 15;
    const int quad = lane >> 4;

    const int bh = blockIdx.y;
    const int b  = bh >> 4;
    const int h  = bh & 15;
    const size_t baseq = (size_t)b * SEQ * LDQ + (size_t)h * HD;
    const size_t basek = baseq + 1024;
    const size_t basev = baseq + 2048;
    const size_t baseo = (size_t)b * SEQ * EMB + (size_t)h * HD;

    // K staging: 64 rows x 64 d; thread -> (row, 8-d chunk). b128 LDS writes.
    const int krow = tid >> 3;           // 0..63
    const int kc0  = (tid & 7) * 8;
    // V staging: wave wv owns d-rows wv*8..wv*8+7, key = lane (conflict-free)
    short* pbase = &lP[(wv * 16) * 72];

    for (int half = 0; half < 2; ++half) {
        const int qtile = half ? (15 - (int)blockIdx.x) : (int)blockIdx.x;
        const int qb = qtile * 128;
        const int qlo = qb + wv * 16;

        // Q fragment (B-operand: n=col -> query, k=quad*8+j). Pre-scaled.
        s16x8 qf[2];
        {
            const short* qr = QKV + baseq + (size_t)(qlo + col) * LDQ;
            qf[0] = *(const s16x8*)(qr + quad * 8);
            qf[1] = *(const s16x8*)(qr + 32 + quad * 8);
        }

        float mrow = -3.0e38f, lrow = 0.f;
        f32x4 of[4];
#pragma unroll
        for (int u = 0; u < 4; ++u) of[u] = (f32x4){0.f, 0.f, 0.f, 0.f};

        const int nt = qb / 64 + 2;

        // prefetch tile 0 into registers
        s16x8 pk = *(const s16x8*)(QKV + basek + (size_t)krow * LDQ + kc0);
        s16x8 pv = *(const s16x8*)(QKV + basev + (size_t)lane * LDQ + wv * 8);

        for (int kt = 0; kt < nt; ++kt) {
            const int kb = kt * 64;
            __syncthreads();                     // LDS free from prev compute
            *(s16x8*)&lK[krow * 72 + kc0] = pk;
#pragma unroll
            for (int t = 0; t < 8; ++t)          // 64 consecutive shorts/instr
                lV[(wv * 8 + t) * 72 + lane] = pv[t];
            __syncthreads();

            // prefetch next tile (overlaps compute)
            if (kt + 1 < nt) {
                pk = *(const s16x8*)(QKV + basek + (size_t)(kb + 64 + krow) * LDQ + kc0);
                pv = *(const s16x8*)(QKV + basev + (size_t)(kb + 64 + lane) * LDQ + wv * 8);
            }

            if (kb > qlo + 15) continue;         // wave fully masked this tile
            const int qg = qlo + col;

            // ---- S^T = K·Q^T : C/D row = key(quad*4+r), col = query ----
            f32x4 s[4];
#pragma unroll
            for (int t = 0; t < 4; ++t) {
                const s16x8 k0 = *(const s16x8*)&lK[(t * 16 + col) * 72 + quad * 8];
                const s16x8 k1 = *(const s16x8*)&lK[(t * 16 + col) * 72 + 32 + quad * 8];
                f32x4 acc = (f32x4){0.f, 0.f, 0.f, 0.f};
                acc = __builtin_amdgcn_mfma_f32_16x16x32_bf16(k0, qf[0], acc, 0, 0, 0);
                acc = __builtin_amdgcn_mfma_f32_16x16x32_bf16(k1, qf[1], acc, 0, 0, 0);
                s[t] = acc;
            }

            if (kb + 63 > qlo) {                 // diagonal tile: causal mask
#pragma unroll
                for (int t = 0; t < 4; ++t)
#pragma unroll
                    for (int rr = 0; rr < 4; ++rr) {
                        const int kg = kb + t * 16 + quad * 4 + rr;
                        if (kg > qg) s[t][rr] = -3.0e38f;
                    }
            }

            float mx = s[0][0];
#pragma unroll
            for (int t = 0; t < 4; ++t)
#pragma unroll
                for (int rr = 0; rr < 4; ++rr) mx = fmaxf(mx, s[t][rr]);
            mx = fmaxf(mx, __shfl_xor(mx, 16, 64));
            mx = fmaxf(mx, __shfl_xor(mx, 32, 64));
            const float mnew = fmaxf(mrow, mx);

            float sum = 0.f;
#pragma unroll
            for (int t = 0; t < 4; ++t)
#pragma unroll
                for (int rr = 0; rr < 4; ++rr) {
                    const float p = __expf(s[t][rr] - mnew);
                    s[t][rr] = p;
                    sum += p;
                }
            sum += __shfl_xor(sum, 16, 64);
            sum += __shfl_xor(sum, 32, 64);

            const float alpha = __expf(mrow - mnew);
            lrow = lrow * alpha + sum;
            mrow = mnew;

            // pack P (bf16) into per-wave staging lP[q][key] (8B stores)
#pragma unroll
            for (int t = 0; t < 4; ++t) {
                uint2 pkd;
                pkd.x = pk_bf16(s[t][0], s[t][1]);
                pkd.y = pk_bf16(s[t][2], s[t][3]);
                *(uint2*)&pbase[col * 72 + t * 16 + quad * 4] = pkd;
            }

            // rescale O^T accumulator: alpha is per-lane (query = col)
#pragma unroll
            for (int u = 0; u < 4; ++u) {
                of[u][0] *= alpha; of[u][1] *= alpha;
                of[u][2] *= alpha; of[u][3] *= alpha;
            }

            // PV: O^T = mfma(A=V^T[d][key], B=P[q][key]) -> D[d][q]
#pragma unroll
            for (int c = 0; c < 2; ++c) {
                const s16x8 pa = *(const s16x8*)&pbase[col * 72 + c * 32 + quad * 8];
#pragma unroll
                for (int u = 0; u < 4; ++u) {
                    const s16x8 vf = *(const s16x8*)&lV[(u * 16 + col) * 72 + c * 32 + quad * 8];
                    of[u] = __builtin_amdgcn_mfma_f32_16x16x32_bf16(vf, pa, of[u], 0, 0, 0);
                }
            }
        }

        // ---- epilogue: per-lane normalize, b64 stores of O[q][d] ----
        const float rl = 1.f / lrow;
        short* orow = O + baseo + (size_t)(qlo + col) * EMB + quad * 4;
#pragma unroll
        for (int u = 0; u < 4; ++u) {
            uint2 pkd;
            pkd.x = pk_bf16(of[u][0] * rl, of[u][1] * rl);
            pkd.y = pk_bf16(of[u][2] * rl, of[u][3] * rl);
            *(uint2*)&orow[u * 16] = pkd;
        }
    }
}

// ---------------------------------------------------------------------------
extern "C" void kernel_launch(void* const* d_in, const int* in_sizes, int n_in,
                              void* d_out, int out_size, void* d_ws, size_t ws_size,
                              hipStream_t stream)
{
    const float* x  = (const float*)d_in[0];
    const float* Wq = (const float*)d_in[1];
    const float* Wk = (const float*)d_in[2];
    const float* Wv = (const float*)d_in[3];
    const float* Wo = (const float*)d_in[4];
    const float* bo = (const float*)d_in[5];
    float* out = (float*)d_out;

    short* xb   = (short*)d_ws;                  // 16 MiB
    short* wcat = xb + XSZ;                      //  8 MiB
    short* qkv  = wcat + 4 * WSZ;                // 48 MiB
    short* ob   = qkv + (size_t)MTOT * 3 * EMB;  // 16 MiB

    const int cvt_blocks = (int)((XSZ + 4 * WSZ) / 8 / 256);   // 6144
    cvt_inputs<<<cvt_blocks, 256, 0, stream>>>(x, Wq, Wk, Wv, Wo, xb, wcat);

    gemm_bf16<true><<<dim3(3072 / 128, MTOT / 128), 256, 0, stream>>>(
        xb, wcat, qkv, 3072, nullptr, EMB);

    attn_mfma<<<dim3(8, BATCH * HEADS), 512, 0, stream>>>(qkv, ob);

    gemm_bf16<false><<<dim3(EMB / 128, MTOT / 128), 256, 0, stream>>>(
        ob, wcat + (size_t)3 * WSZ, out, EMB, bo, EMB);
}